// Round 16
// baseline (20.682 us; speedup 1.0000x reference)
//
#include <hip/hip_runtime.h>
#include <stdint.h>

#define CN 144
#define VN 576
#define BN 1024
#define NITER 3
#define RCAP 32      // row-weight capacity, multiple of 4 (actual max ~28; R9-R15-proven)
#define NQ   (RCAP/4)
#define CCAP 8       // column-weight capacity (actual 4, rare 5)
#define TPB 192      // 3 waves; 576/192 = exactly 3 columns per thread (R11/R15-proven)

// ws layout (ints):
#define WS_RLEN 0                 // [0,144)   raw row lengths (redundant same-value writes)
#define WS_CSC  160               // [160, 160+VN*8) AoS per column: 8 entries; entry 0
                                  // bits[24:28] = cnt, bits[0:24] = edge id; entries 1..7 = ids

// edge id for (row-slot l, check c), quad layout: float index
// ((l>>2)*CN + c)*4 + (l&3) -> lane-consecutive float4 per (l>>2, c)
__device__ __forceinline__ int edge_id(int l, int c) {
    return (((l >> 2) * CN + c) << 2) | (l & 3);
}

// ---- single build kernel (R15-proven structure): one wave per column.
// Member checks via chunked column ballot (ascending c); per member row the
// ascending-v slot (prefix popcount) and raw row length via 9 coalesced
// chunk-ballots. Only change vs R15: CSC written AoS [v][8] with cnt packed
// into entry 0 (bits 24..27). Bit-identical graph content.
__global__ __launch_bounds__(64) void build_combined(const float* __restrict__ H,
                                                     int* __restrict__ ws) {
    const int v = blockIdx.x;          // 576 blocks
    const int lane = threadIdx.x;      // 64
    __shared__ int rows[CCAP];         // member check ids, ascending c

    int cn = 0;                        // wave-uniform running count
    for (int ch = 0; ch < 3; ++ch) {
        const int c = ch * 64 + lane;
        const bool set = (c < CN) && (H[c * VN + v] > 0.5f);
        const unsigned long long mask = __ballot(set);
        const int off = cn + (int)__popcll(mask & ((1ULL << lane) - 1ULL));
        if (set && off < CCAP) rows[off] = c;
        cn += (int)__popcll(mask);
    }
    const int nr = min(cn, CCAP);
    __syncthreads();                   // publish rows[] (1 wave: cheap)

    const int vch = v >> 6, vbit = v & 63;
    for (int j = 0; j < nr; ++j) {
        const int c = rows[j];         // wave-uniform
        int pre = 0, tot = 0;
        for (int ch = 0; ch < 9; ++ch) {               // coalesced row sweep
            const bool s = H[c * VN + ch * 64 + lane] > 0.5f;
            const unsigned long long m = __ballot(s);
            tot += (int)__popcll(m);
            if (ch < vch)       pre += (int)__popcll(m);
            else if (ch == vch) pre += (int)__popcll(m & ((1ULL << vbit) - 1ULL));
        }
        if (lane == 0) {
            int e = (pre < RCAP) ? edge_id(pre, c) : 0;
            if (j == 0) e |= (nr << 24);               // pack cnt into entry 0
            ws[WS_CSC + v * 8 + j] = e;
            ws[WS_RLEN + c] = tot;     // identical value from every column of c
        }
    }
    if (lane == 0 && nr == 0) ws[WS_CSC + v * 8] = 0;  // unreachable (col weight>=4)
    if (lane >= nr && lane < CCAP) ws[WS_CSC + v * 8 + lane] = 0;  // defined, unused
}

// ---- decode: R15/R11 body; only the init loads changed (AoS int4 + packed cnt) ----
__global__ __launch_bounds__(TPB) void ldpc_decode(const float* __restrict__ r,
                                                   const float* __restrict__ alpha,
                                                   const int* __restrict__ ws,
                                                   float* __restrict__ out) {
    __shared__ float4 M4[NQ * CN];     // 18.4 KB
    float* const Mf = reinterpret_cast<float*>(M4);

    const int b = blockIdx.x;
    const int t = threadIdx.x;
    const float a_[NITER] = { alpha[0], alpha[1], alpha[2] };

    // per-thread columns v = t + q*TPB: ONE dwordx4 gives cnt + 4 edge ids
    int ent4[3][4], entX[3][4];
    int cnt[3];
    float rv[3];
    #pragma unroll
    for (int q = 0; q < 3; ++q) {
        const int v = t + q * TPB;
        rv[q] = r[b * VN + v];
        const int4 eA = *reinterpret_cast<const int4*>(ws + WS_CSC + v * 8);
        cnt[q] = (eA.x >> 24) & 0xF;
        ent4[q][0] = eA.x & 0x00FFFFFF;
        ent4[q][1] = eA.y; ent4[q][2] = eA.z; ent4[q][3] = eA.w;
    }
    const int rl = (t < CN) ? min(ws[WS_RLEN + t], RCAP) : 0;
    const int any_hi = __syncthreads_or((cnt[0] > 4) | (cnt[1] > 4) | (cnt[2] > 4));
    if (any_hi) {
        #pragma unroll
        for (int q = 0; q < 3; ++q) {
            const int4 eB = *reinterpret_cast<const int4*>(ws + WS_CSC + (t + q * TPB) * 8 + 4);
            entX[q][0] = eB.x; entX[q][1] = eB.y; entX[q][2] = eB.z; entX[q][3] = eB.w;
        }
    }

    // INF pads up to quad boundary (preserved across iterations)
    if (t < CN) {
        const int rpad = (rl + 3) & ~3;
        for (int k = rl; k < rpad; ++k) Mf[edge_id(k, t)] = INFINITY;
    }
    // M init = r on real edges (disjoint from pads)
    #pragma unroll
    for (int q = 0; q < 3; ++q) {
        #pragma unroll
        for (int j = 0; j < 4; ++j) if (j < cnt[q]) Mf[ent4[q][j]] = rv[q];
    }
    if (any_hi) {
        #pragma unroll
        for (int q = 0; q < 3; ++q) {
            #pragma unroll
            for (int j = 0; j < 4; ++j) if (4 + j < cnt[q]) Mf[entX[q][j]] = rv[q];
        }
    }
    __syncthreads();

    #pragma unroll
    for (int it = 0; it < NITER; ++it) {
        const float a = a_[it];

        // Pass A: 5-op two-smallest scan (no argmin), register-cached quads,
        // writeback E in place with equality-based exclusion (bit-exact).
        if (t < CN) {
            const int nq  = (rl + 3) >> 2;
            const int nqf = rl >> 2;
            float4 mq[NQ];                          // statically indexed (unrolled)
            uint32_t m1 = 0x7fffffffu, m2 = 0x7fffffffu, sg = 0u;
            #pragma unroll
            for (int q4 = 0; q4 < NQ; ++q4) {
                if (q4 < nq) {
                    mq[q4] = M4[q4 * CN + t];
                    const uint32_t* mu = reinterpret_cast<const uint32_t*>(&mq[q4]);
                    #pragma unroll
                    for (int j = 0; j < 4; ++j) {
                        const uint32_t mb = mu[j];
                        const uint32_t ab = mb & 0x7fffffffu;  // INF pads never win
                        sg ^= mb;
                        const uint32_t hi = (ab > m1) ? ab : m1;
                        m1 = (ab < m1) ? ab : m1;
                        m2 = (hi < m2) ? hi : m2;
                    }
                }
            }
            sg &= 0x80000000u;                              // pads are +INF: sign +1
            const uint32_t p1b = __float_as_uint(a * __uint_as_float(m1)) ^ sg;
            const uint32_t p2b = __float_as_uint(a * __uint_as_float(m2)) ^ sg;
            // exclusion by ab==m1: unique min -> exact argmin; ties -> p1b==p2b
            #pragma unroll
            for (int q4 = 0; q4 < NQ; ++q4) {
                if (q4 < nq) {
                    const uint32_t* mu = reinterpret_cast<const uint32_t*>(&mq[q4]);
                    float4 ev;
                    uint32_t* eu = reinterpret_cast<uint32_t*>(&ev);
                    if (q4 < nqf) {                         // full quad
                        #pragma unroll
                        for (int j = 0; j < 4; ++j) {
                            const uint32_t mb = mu[j];
                            const uint32_t ab = mb & 0x7fffffffu;
                            eu[j] = ((ab == m1) ? p2b : p1b) ^ (mb & 0x80000000u);
                        }
                    } else {                                // tail quad: keep INF pads
                        #pragma unroll
                        for (int j = 0; j < 4; ++j) {
                            const int k = q4 * 4 + j;
                            const uint32_t mb = mu[j];
                            const uint32_t ab = mb & 0x7fffffffu;
                            eu[j] = (k < rl)
                                  ? (((ab == m1) ? p2b : p1b) ^ (mb & 0x80000000u))
                                  : mb;
                        }
                    }
                    M4[q4 * CN + t] = ev;
                }
            }
        }
        __syncthreads();

        // Pass B: per-column gather of E (ascending c), col-sum, fused M update
        #pragma unroll
        for (int q = 0; q < 3; ++q) {
            float E4[4], EX[4];
            float col = 0.0f;
            #pragma unroll
            for (int j = 0; j < 4; ++j) {
                E4[j] = (j < cnt[q]) ? Mf[ent4[q][j]] : 0.0f;
                col += E4[j];
            }
            if (any_hi) {
                #pragma unroll
                for (int j = 0; j < 4; ++j) {
                    EX[j] = (4 + j < cnt[q]) ? Mf[entX[q][j]] : 0.0f;
                    col += EX[j];
                }
            }
            if (it == NITER - 1) {
                out[b * VN + t + q * TPB] = rv[q] + col;
            } else {
                const float mb = col + rv[q];
                #pragma unroll
                for (int j = 0; j < 4; ++j) if (j < cnt[q]) Mf[ent4[q][j]] = mb - E4[j];
                if (any_hi) {
                    #pragma unroll
                    for (int j = 0; j < 4; ++j) if (4 + j < cnt[q]) Mf[entX[q][j]] = mb - EX[j];
                }
            }
        }
        if (it < NITER - 1) __syncthreads();
    }
}

extern "C" void kernel_launch(void* const* d_in, const int* in_sizes, int n_in,
                              void* d_out, int out_size, void* d_ws, size_t ws_size,
                              hipStream_t stream) {
    const float* r     = (const float*)d_in[0];
    const float* alpha = (const float*)d_in[1];
    const float* H     = (const float*)d_in[2];
    float* out = (float*)d_out;
    int* ws    = (int*)d_ws;

    build_combined<<<VN, 64, 0, stream>>>(H, ws);
    ldpc_decode<<<BN, TPB, 0, stream>>>(r, alpha, ws, out);
}